// Round 13
// baseline (1076.884 us; speedup 1.0000x reference)
//
#include <hip/hip_runtime.h>
#include <hip/hip_bf16.h>

#define BB 4096
#define TT 512
#define HH 256

typedef __bf16 bf16x8 __attribute__((ext_vector_type(8)));
typedef __bf16 bf16x4 __attribute__((ext_vector_type(4)));
typedef float f32x4 __attribute__((ext_vector_type(4)));
typedef long fp8frag;  // 8 x e4m3 in 2 VGPRs

#define MFMA_BF16 __builtin_amdgcn_mfma_f32_16x16x32_bf16
#define MFMA_FP8  __builtin_amdgcn_mfma_f32_16x16x32_fp8_fp8

#if defined(__has_builtin)
#if __has_builtin(__builtin_amdgcn_exp2f)
#define EXP2F(x) __builtin_amdgcn_exp2f(x)
#endif
#endif
#ifndef EXP2F
#define EXP2F(x) __expf((x) * 0.6931471805599453f)
#endif
#define RCPF(x) __builtin_amdgcn_rcpf(x)

#define L2E  1.4426950408889634f
#define TL2E 2.8853900817779268f   // 2*log2e
#define HL2E 0.7213475204444817f   // 0.5*log2e

// OPERAND-SWAP LAYOUT (r12): A = W (fp8, x64), B = h (fp8, x16); MFMA output
// D[unit][batch]: col=lane&15=batch row, row=(lane>>4)*4+j = 4 CONSECUTIVE
// units -> contiguous h-writes, shfl-free heads.
// Extended K = 288: k=256 -> x (x16 on B / w_ih x64 on A), k=257 -> 1 (=16 on
// B / bias x64 on A), k>=258 zeros. wB8[((ctg*9+kt)*64+l)*8+e], 294912 B.
__global__ void prep_weights8(const float* __restrict__ w_hh, const float* __restrict__ w_ih,
                              const float* __restrict__ b_ih, const float* __restrict__ b_hh,
                              char* __restrict__ wB8) {
    int idx = blockIdx.x * blockDim.x + threadIdx.x;
    if (idx >= 64 * 9 * 64) return;
    int l = idx & 63;
    int kt = (idx >> 6) % 9;
    int ctg = idx / (9 * 64);
    int n = ctg * 16 + (l & 15);
    int k0 = kt * 32 + 8 * (l >> 4);
    float f[8];
#pragma unroll
    for (int e = 0; e < 8; ++e) {
        int k = k0 + e;
        float v = 0.f;
        if (k < 256) v = w_hh[n * HH + k];
        else if (k == 256) v = w_ih[n];
        else if (k == 257) v = b_ih[n] + b_hh[n];
        f[e] = v * 64.f;
    }
    int lo = __builtin_amdgcn_cvt_pk_fp8_f32(f[0], f[1], 0, false);
    lo = __builtin_amdgcn_cvt_pk_fp8_f32(f[2], f[3], lo, true);
    int hi = __builtin_amdgcn_cvt_pk_fp8_f32(f[4], f[5], 0, false);
    hi = __builtin_amdgcn_cvt_pk_fp8_f32(f[6], f[7], hi, true);
    int2 v; v.x = lo; v.y = hi;
    *(int2*)(wB8 + (size_t)idx * 8) = v;
}

// exp2-domain activations (v_exp_f32 IS 2^x); inputs pre-scaled by log2e.
#define SGg(v) RCPF(1.f + EXP2F(-(v)))
#define THg(v) (1.f - 2.f * RCPF(EXP2F(v) + 1.f))

// STALL-STRIP (r13): (1) all 9 hbuf8 frags prefetched to regs after the
// barrier (P0+P1 consume regs; 18->9 ds_reads, zero LDS latency inside the
// MFMA chains); (2) cc6 LDS->wreg (45 frags / 90 regs) so P1 is fully
// register-fed. Arch estimate ~128 (granted 92 in r12, cap >=128; FETCH is
// the spill tripwire).
__global__ __launch_bounds__(512, 1) void lstm_fused(
    const float* __restrict__ x, const float* __restrict__ eps,
    const float* __restrict__ w_mean, const float* __restrict__ b_mean,
    const float* __restrict__ w_logvar, const float* __restrict__ b_logvar,
    const char* __restrict__ wB8, float* __restrict__ out)
{
    __shared__ __align__(16) char wlds8[8][18][512];    // 73728 B: cc2, cc3
    __shared__ __align__(16) __bf16 hbuf[2][16][296];   // 18944 B: bf16 h|x|1 (heads)
    __shared__ __align__(16) char hbuf8[2][16][296];    // 9472 B: fp8 (h|x)*16, 1*16
    __shared__ __align__(16) __bf16 headw[9][512];      // 9216 B
    __shared__ float obuf[2][16][16];                   // 2048 B: mean, logvar(clipped)
    // total 113408 B

    const int tid = threadIdx.x;
    const int w = tid >> 6;          // wave 0..7
    const int l = tid & 63;
    const int m0 = blockIdx.x * 16;

    for (int i = tid; i < 2 * 16 * 296; i += 512) (&hbuf[0][0][0])[i] = (__bf16)0.f;
    for (int i = tid; i < 2 * 16 * 296; i += 512) (&hbuf8[0][0][0])[i] = 0;
    // headw A-frags: row 0 = w_mean, row 1 = w_logvar (k=257 -> biases)
    for (int i = tid; i < 9 * 64; i += 512) {
        int kt = i >> 6, hl = i & 63;
        int col = hl & 15;
        int k0 = kt * 32 + 8 * (hl >> 4);
        bf16x8 hw;
#pragma unroll
        for (int e = 0; e < 8; ++e) {
            int k = k0 + e;
            float v = 0.f;
            if (k < 256) {
                if (col == 0) v = w_mean[k];
                else if (col == 1) v = w_logvar[k];
            } else if (k == 257) {
                if (col == 0) v = b_mean[0];
                else if (col == 1) v = b_logvar[0];
            }
            hw[e] = (__bf16)v;
        }
        *(bf16x8*)&headw[kt][hl * 8] = hw;
    }

    // wave w owns ctg = w + 8p + 16g for cc = p*4+g.
    // wreg: cc0 (w), cc1 (w+16), cc4 (w+8), cc5 (w+24), cc6 (w+40) [45 frags]
    // LDS : cc2 (w+32), cc3 (w+48)                                 [18 frags]
    // stream: cc7 (w+56)                                           [9 frags]
    fp8frag wreg8[45];
#pragma unroll
    for (int kt = 0; kt < 9; ++kt) {
        wreg8[kt]      = *(const fp8frag*)(wB8 + ((size_t)((w)      * 9 + kt) * 64 + l) * 8);
        wreg8[9 + kt]  = *(const fp8frag*)(wB8 + ((size_t)((w + 16) * 9 + kt) * 64 + l) * 8);
        wreg8[18 + kt] = *(const fp8frag*)(wB8 + ((size_t)((w + 8)  * 9 + kt) * 64 + l) * 8);
        wreg8[27 + kt] = *(const fp8frag*)(wB8 + ((size_t)((w + 24) * 9 + kt) * 64 + l) * 8);
        wreg8[36 + kt] = *(const fp8frag*)(wB8 + ((size_t)((w + 40) * 9 + kt) * 64 + l) * 8);
        *(fp8frag*)&wlds8[w][kt][l * 8] =
            *(const fp8frag*)(wB8 + ((size_t)((w + 32) * 9 + kt) * 64 + l) * 8);
        *(fp8frag*)&wlds8[w][9 + kt][l * 8] =
            *(const fp8frag*)(wB8 + ((size_t)((w + 48) * 9 + kt) * 64 + l) * 8);
    }
    const char* pc7 = wB8 + ((size_t)((w + 56) * 9 + 4) * 64 + l) * 8;  // kt anchor 4

    const int arow = l & 15;
    const int ako = 8 * (l >> 4);
    const int u0 = 16 * w + ((l >> 4) << 2);   // 4 consecutive units
    const int u1 = u0 + 128;

    const float DS1c = L2E / 1024.f;   // acc descale * log2e
    const float DS2c = TL2E / 1024.f;  // acc descale * 2*log2e (g-gate)

    float c[8];
#pragma unroll
    for (int i = 0; i < 8; ++i) c[i] = 0.f;
    const f32x4 Z = {0.f, 0.f, 0.f, 0.f};

    __syncthreads();
    if (tid < 16) {
        hbuf[0][tid][257] = (__bf16)1.0f;
        hbuf[1][tid][257] = (__bf16)1.0f;
        hbuf8[0][tid][257] = (char)__builtin_amdgcn_cvt_pk_fp8_f32(16.f, 0.f, 0, false);
        hbuf8[1][tid][257] = (char)__builtin_amdgcn_cvt_pk_fp8_f32(16.f, 0.f, 0, false);
        float x0 = x[(size_t)(m0 + tid) * TT];
        hbuf[1][tid][256] = (__bf16)x0;                 // rb of t=0 is buf 1
        hbuf8[1][tid][256] = (char)__builtin_amdgcn_cvt_pk_fp8_f32(x0 * 16.f, 0.f, 0, false);
    }
    fp8frag sbf = *(const fp8frag*)(pc7 - 2048);  // stream kt0 for t=0
    fp8frag tbf;
    __syncthreads();

#define P0KT(KT)                                                                \
    do {                                                                        \
        a0 = MFMA_FP8(wreg8[KT], hf[KT], (KT) ? a0 : Z, 0, 0, 0);               \
        a1 = MFMA_FP8(wreg8[9 + (KT)], hf[KT], (KT) ? a1 : Z, 0, 0, 0);         \
        a2 = MFMA_FP8(*(const fp8frag*)&wlds8[w][KT][l * 8], hf[KT], (KT) ? a2 : Z, 0, 0, 0);       \
        a3 = MFMA_FP8(*(const fp8frag*)&wlds8[w][9 + (KT)][l * 8], hf[KT], (KT) ? a3 : Z, 0, 0, 0); \
    } while (0)

#define P1KT(KT, NXT, USE, PF)                                                  \
    do {                                                                        \
        PF = *(const fp8frag*)(pc7 + ((NXT) - 4) * 512);                        \
        a4 = MFMA_FP8(wreg8[18 + (KT)], hf[KT], (KT) ? a4 : Z, 0, 0, 0);        \
        a5 = MFMA_FP8(wreg8[27 + (KT)], hf[KT], (KT) ? a5 : Z, 0, 0, 0);        \
        a6 = MFMA_FP8(wreg8[36 + (KT)], hf[KT], (KT) ? a6 : Z, 0, 0, 0);        \
        a7 = MFMA_FP8(USE, hf[KT], (KT) ? a7 : Z, 0, 0, 0);                     \
    } while (0)

#define EWP0C(J)                                                                \
    do {                                                                        \
        float gi_ = a0[J] * DS1c, gf_ = a1[J] * DS1c;                           \
        float gg_ = a2[J] * DS2c, go_ = a3[J] * DS1c;                           \
        float cn_ = fmaf(SGg(gf_), c[J], SGg(gi_) * THg(gg_));                  \
        c[J] = cn_;                                                             \
        hA[J] = SGg(go_) * THg(cn_ * TL2E);                                     \
    } while (0)

#define EWP1C(J)                                                                \
    do {                                                                        \
        float gi_ = a4[J] * DS1c, gf_ = a5[J] * DS1c;                           \
        float gg_ = a6[J] * DS2c, go_ = a7[J] * DS1c;                           \
        float cn_ = fmaf(SGg(gf_), c[4 + (J)], SGg(gi_) * THg(gg_));            \
        c[4 + (J)] = cn_;                                                       \
        hB[J] = SGg(go_) * THg(cn_ * TL2E);                                     \
    } while (0)

#define WRH(PB, HV, U)                                                          \
    do {                                                                        \
        bf16x4 hb_ = {(__bf16)HV[0], (__bf16)HV[1], (__bf16)HV[2], (__bf16)HV[3]};\
        *(bf16x4*)&hbuf[PB][arow][U] = hb_;                                     \
        int pk_ = __builtin_amdgcn_cvt_pk_fp8_f32(HV[0] * 16.f, HV[1] * 16.f, 0, false);\
        pk_ = __builtin_amdgcn_cvt_pk_fp8_f32(HV[2] * 16.f, HV[3] * 16.f, pk_, true);  \
        *(int*)&hbuf8[PB][arow][U] = pk_;                                       \
    } while (0)

#define HEADS(RB, SLOT)                                                         \
    do {                                                                        \
        f32x4 ah_;                                                              \
        {                                                                       \
            bf16x8 hb_ = *(const bf16x8*)&hbuf[RB][arow][0 * 32 + ako];         \
            ah_ = MFMA_BF16(*(const bf16x8*)&headw[0][l * 8], hb_, Z, 0, 0, 0); \
        }                                                                       \
        _Pragma("unroll")                                                       \
        for (int kt_ = 1; kt_ < 9; ++kt_) {                                     \
            bf16x8 hb_ = *(const bf16x8*)&hbuf[RB][arow][kt_ * 32 + ako];       \
            ah_ = MFMA_BF16(*(const bf16x8*)&headw[kt_][l * 8], hb_, ah_, 0, 0, 0);\
        }                                                                       \
        if (l < 16) {                                                           \
            obuf[0][l][SLOT] = ah_[0];                                          \
            obuf[1][l][SLOT] = fminf(fmaxf(ah_[1], -10.f), 2.f);                \
        }                                                                       \
    } while (0)

#define FLUSH(T0)                                                               \
    do {                                                                        \
        if (tid < 192) {                                                        \
            const int o_ = tid >> 6, rr_ = (tid >> 2) & 15, q_ = tid & 3;       \
            f32x4 mv_ = *(const f32x4*)&obuf[0][rr_][q_ * 4];                   \
            f32x4 lv_ = *(const f32x4*)&obuf[1][rr_][q_ * 4];                   \
            const size_t base_ = (size_t)(m0 + rr_) * TT + (T0) + q_ * 4;       \
            if (o_ == 0) {                                                      \
                f32x4 e_ = *(const f32x4*)&eps[base_];                          \
                f32x4 s_;                                                       \
                _Pragma("unroll")                                               \
                for (int k_ = 0; k_ < 4; ++k_)                                  \
                    s_[k_] = fmaf(EXP2F(lv_[k_] * HL2E), e_[k_], mv_[k_]);      \
                *(f32x4*)&out[base_] = s_;                                      \
            } else if (o_ == 1) {                                               \
                *(f32x4*)&out[(size_t)BB * TT + base_] = mv_;                   \
            } else {                                                            \
                *(f32x4*)&out[2 * (size_t)BB * TT + base_] = lv_;               \
            }                                                                   \
        }                                                                       \
    } while (0)

#define STEP(PB, RB, BA, BX)                                                    \
    do {                                                                        \
        const int tt = t0 + (PB);                                               \
        float xn = 0.f;                                                         \
        if (tid < 16 && tt + 1 < TT) xn = x[(size_t)(m0 + tid) * TT + (tt + 1)];\
        fp8frag hf[9];                                                          \
        _Pragma("unroll")                                                       \
        for (int kt_ = 0; kt_ < 9; ++kt_)                                       \
            hf[kt_] = *(const fp8frag*)&hbuf8[RB][arow][kt_ * 32 + ako];        \
        f32x4 a0, a1, a2, a3, a4, a5, a6, a7;                                   \
        float hA[4], hB[4];                                                     \
        P0KT(0); P0KT(1); P0KT(2); P0KT(3); P0KT(4);                            \
        P0KT(5); P0KT(6); P0KT(7); P0KT(8);                                     \
        P1KT(0, 1, BA, BX); P1KT(1, 2, BX, BA); EWP0C(0);                       \
        P1KT(2, 3, BA, BX); P1KT(3, 4, BX, BA); EWP0C(1);                       \
        P1KT(4, 5, BA, BX); P1KT(5, 6, BX, BA); EWP0C(2);                       \
        P1KT(6, 7, BA, BX); P1KT(7, 8, BX, BA); EWP0C(3);                       \
        P1KT(8, 0, BA, BX);                                                     \
        WRH(PB, hA, u0);                                                        \
        if (w == 7 && tt >= 1) { HEADS(RB, (tt - 1) & 15); }                    \
        EWP1C(0); EWP1C(1); EWP1C(2); EWP1C(3);                                 \
        WRH(PB, hB, u1);                                                        \
        if (tid < 16 && tt + 1 < TT) {                                          \
            hbuf[PB][tid][256] = (__bf16)xn;                                    \
            hbuf8[PB][tid][256] =                                               \
                (char)__builtin_amdgcn_cvt_pk_fp8_f32(xn * 16.f, 0.f, 0, false);\
        }                                                                       \
        if ((PB) == 0 && tt > 0 && (tt & 15) == 0) {                            \
            __syncthreads();                                                    \
            FLUSH(tt - 16);                                                     \
        }                                                                       \
        __syncthreads();                                                        \
    } while (0)

    for (int t0 = 0; t0 < TT; t0 += 2) {
        STEP(0, 1, sbf, tbf);
        STEP(1, 0, tbf, sbf);
    }

    // ---- tail: head for h_{TT-1} (in hbuf[1]) + final flush ----
    if (w == 7) { HEADS(1, 15); }
    __syncthreads();
    FLUSH(TT - 16);

#undef P0KT
#undef P1KT
#undef EWP0C
#undef EWP1C
#undef WRH
#undef HEADS
#undef FLUSH
#undef STEP
}

extern "C" void kernel_launch(void* const* d_in, const int* in_sizes, int n_in,
                              void* d_out, int out_size, void* d_ws, size_t ws_size,
                              hipStream_t stream) {
    const float* x = (const float*)d_in[0];
    const float* eps = (const float*)d_in[1];
    const float* w_ih = (const float*)d_in[2];
    const float* w_hh = (const float*)d_in[3];
    const float* b_ih = (const float*)d_in[4];
    const float* b_hh = (const float*)d_in[5];
    const float* w_mean = (const float*)d_in[6];
    const float* b_mean = (const float*)d_in[7];
    const float* w_logvar = (const float*)d_in[8];
    const float* b_logvar = (const float*)d_in[9];

    char* wB8 = (char*)d_ws;  // 288 KB fp8 A-frag weights (x64, K=288 fold)

    prep_weights8<<<144, 256, 0, stream>>>(w_hh, w_ih, b_ih, b_hh, wB8);
    lstm_fused<<<256, 512, 0, stream>>>(x, eps, w_mean, b_mean, w_logvar, b_logvar,
                                        wB8, (float*)d_out);
}

// Round 14
// 1075.771 us; speedup vs baseline: 1.0010x; 1.0010x over previous
//
#include <hip/hip_runtime.h>
#include <hip/hip_bf16.h>

#define BB 4096
#define TT 512
#define HH 256

typedef __bf16 bf16x8 __attribute__((ext_vector_type(8)));
typedef __bf16 bf16x4 __attribute__((ext_vector_type(4)));
typedef float f32x4 __attribute__((ext_vector_type(4)));
typedef long fp8frag;  // 8 x e4m3 in 2 VGPRs

#define MFMA_BF16 __builtin_amdgcn_mfma_f32_16x16x32_bf16
#define MFMA_FP8  __builtin_amdgcn_mfma_f32_16x16x32_fp8_fp8

#if defined(__has_builtin)
#if __has_builtin(__builtin_amdgcn_exp2f)
#define EXP2F(x) __builtin_amdgcn_exp2f(x)
#endif
#endif
#ifndef EXP2F
#define EXP2F(x) __expf((x) * 0.6931471805599453f)
#endif
#define RCPF(x) __builtin_amdgcn_rcpf(x)

#define L2E  1.4426950408889634f
#define TL2E 2.8853900817779268f   // 2*log2e
#define HL2E 0.7213475204444817f   // 0.5*log2e

// OPERAND-SWAP LAYOUT (r12): A = W (fp8, x64), B = h (fp8, x16); MFMA output
// D[unit][batch]: col=lane&15=batch row, row=(lane>>4)*4+j = 4 CONSECUTIVE
// units. Extended K = 288: k=256 -> x, k=257 -> 1 (bias), k>=258 zeros.
// wB8[((ctg*9+kt)*64+l)*8+e], 294912 B.
__global__ void prep_weights8(const float* __restrict__ w_hh, const float* __restrict__ w_ih,
                              const float* __restrict__ b_ih, const float* __restrict__ b_hh,
                              char* __restrict__ wB8) {
    int idx = blockIdx.x * blockDim.x + threadIdx.x;
    if (idx >= 64 * 9 * 64) return;
    int l = idx & 63;
    int kt = (idx >> 6) % 9;
    int ctg = idx / (9 * 64);
    int n = ctg * 16 + (l & 15);
    int k0 = kt * 32 + 8 * (l >> 4);
    float f[8];
#pragma unroll
    for (int e = 0; e < 8; ++e) {
        int k = k0 + e;
        float v = 0.f;
        if (k < 256) v = w_hh[n * HH + k];
        else if (k == 256) v = w_ih[n];
        else if (k == 257) v = b_ih[n] + b_hh[n];
        f[e] = v * 64.f;
    }
    int lo = __builtin_amdgcn_cvt_pk_fp8_f32(f[0], f[1], 0, false);
    lo = __builtin_amdgcn_cvt_pk_fp8_f32(f[2], f[3], lo, true);
    int hi = __builtin_amdgcn_cvt_pk_fp8_f32(f[4], f[5], 0, false);
    hi = __builtin_amdgcn_cvt_pk_fp8_f32(f[6], f[7], hi, true);
    int2 v; v.x = lo; v.y = hi;
    *(int2*)(wB8 + (size_t)idx * 8) = v;
}

// exp2-domain activations (v_exp_f32 IS 2^x); inputs pre-scaled by log2e.
#define SGg(v) RCPF(1.f + EXP2F(-(v)))
#define THg(v) (1.f - 2.f * RCPF(EXP2F(v) + 1.f))

// SPLIT-BARRIER DEFERRED-EWB SCHEDULE (r14): GEMM k-tiles read disjoint h
// column ranges: kt0-3 -> units 0-127 (group A), kt4-7 -> units 128-255
// (group B), kt8 -> x/bias. Phase1 (kt{0,1,2,3,8}, 40 MFMAs/wave) hides the
// DEFERRED group-B cell update of step t-1 (gates kept in sa4-7 across the
// barrier; its writes hit cols 128-255 of the read buffer = not read in
// phase1). Mid-barrier. Phase2 (kt{4,5,6,7}): a0-a3 finish first, then a4-a7
// with EWA interleaved. Heads chain split 5/4 across phases (wave 7).
__global__ __launch_bounds__(512, 1) void lstm_fused(
    const float* __restrict__ x, const float* __restrict__ eps,
    const float* __restrict__ w_mean, const float* __restrict__ b_mean,
    const float* __restrict__ w_logvar, const float* __restrict__ b_logvar,
    const char* __restrict__ wB8, float* __restrict__ out)
{
    __shared__ __align__(16) char wlds8[8][18][512];    // 73728 B: cc2, cc3
    __shared__ __align__(16) __bf16 hbuf[2][16][296];   // 18944 B: bf16 h|x|1 (heads)
    __shared__ __align__(16) char hbuf8[2][16][296];    // 9472 B: fp8 (h|x)*16, 1*16
    __shared__ __align__(16) __bf16 headw[9][512];      // 9216 B
    __shared__ float obuf[2][16][16];                   // 2048 B: mean, logvar(clipped)
    // total 113408 B

    const int tid = threadIdx.x;
    const int w = tid >> 6;          // wave 0..7
    const int l = tid & 63;
    const int m0 = blockIdx.x * 16;

    for (int i = tid; i < 2 * 16 * 296; i += 512) (&hbuf[0][0][0])[i] = (__bf16)0.f;
    for (int i = tid; i < 2 * 16 * 296; i += 512) (&hbuf8[0][0][0])[i] = 0;
    // headw A-frags: row 0 = w_mean, row 1 = w_logvar (k=257 -> biases)
    for (int i = tid; i < 9 * 64; i += 512) {
        int kt = i >> 6, hl = i & 63;
        int col = hl & 15;
        int k0 = kt * 32 + 8 * (hl >> 4);
        bf16x8 hw;
#pragma unroll
        for (int e = 0; e < 8; ++e) {
            int k = k0 + e;
            float v = 0.f;
            if (k < 256) {
                if (col == 0) v = w_mean[k];
                else if (col == 1) v = w_logvar[k];
            } else if (k == 257) {
                if (col == 0) v = b_mean[0];
                else if (col == 1) v = b_logvar[0];
            }
            hw[e] = (__bf16)v;
        }
        *(bf16x8*)&headw[kt][hl * 8] = hw;
    }

    // wave w owns ctg = w + 8p + 16g for cc = p*4+g.
    // wreg: cc0 (w), cc1 (w+16), cc4 (w+8), cc5 (w+24), cc6 (w+40) [45 frags]
    // LDS : cc2 (w+32), cc3 (w+48); stream: cc7 (w+56)
    fp8frag wreg8[45];
#pragma unroll
    for (int kt = 0; kt < 9; ++kt) {
        wreg8[kt]      = *(const fp8frag*)(wB8 + ((size_t)((w)      * 9 + kt) * 64 + l) * 8);
        wreg8[9 + kt]  = *(const fp8frag*)(wB8 + ((size_t)((w + 16) * 9 + kt) * 64 + l) * 8);
        wreg8[18 + kt] = *(const fp8frag*)(wB8 + ((size_t)((w + 8)  * 9 + kt) * 64 + l) * 8);
        wreg8[27 + kt] = *(const fp8frag*)(wB8 + ((size_t)((w + 24) * 9 + kt) * 64 + l) * 8);
        wreg8[36 + kt] = *(const fp8frag*)(wB8 + ((size_t)((w + 40) * 9 + kt) * 64 + l) * 8);
        *(fp8frag*)&wlds8[w][kt][l * 8] =
            *(const fp8frag*)(wB8 + ((size_t)((w + 32) * 9 + kt) * 64 + l) * 8);
        *(fp8frag*)&wlds8[w][9 + kt][l * 8] =
            *(const fp8frag*)(wB8 + ((size_t)((w + 48) * 9 + kt) * 64 + l) * 8);
    }
    const char* pc7 = wB8 + ((size_t)((w + 56) * 9 + 4) * 64 + l) * 8;  // kt anchor 4

    const int arow = l & 15;
    const int ako = 8 * (l >> 4);
    const int u0 = 16 * w + ((l >> 4) << 2);   // 4 consecutive units
    const int u1 = u0 + 128;

    const float DS1c = L2E / 1024.f;   // acc descale * log2e
    const float DS2c = TL2E / 1024.f;  // acc descale * 2*log2e (g-gate)

    float c[8];
#pragma unroll
    for (int i = 0; i < 8; ++i) c[i] = 0.f;
    const f32x4 Z = {0.f, 0.f, 0.f, 0.f};
    f32x4 sa4 = Z, sa5 = Z, sa6 = Z, sa7 = Z;   // deferred group-B gates

    __syncthreads();
    if (tid < 16) {
        hbuf[0][tid][257] = (__bf16)1.0f;
        hbuf[1][tid][257] = (__bf16)1.0f;
        hbuf8[0][tid][257] = (char)__builtin_amdgcn_cvt_pk_fp8_f32(16.f, 0.f, 0, false);
        hbuf8[1][tid][257] = (char)__builtin_amdgcn_cvt_pk_fp8_f32(16.f, 0.f, 0, false);
        float x0 = x[(size_t)(m0 + tid) * TT];
        hbuf[1][tid][256] = (__bf16)x0;                 // rb of t=0 is buf 1
        hbuf8[1][tid][256] = (char)__builtin_amdgcn_cvt_pk_fp8_f32(x0 * 16.f, 0.f, 0, false);
    }
    fp8frag sbf = *(const fp8frag*)(pc7 - 2048);  // stream kt0 for t=0
    fp8frag tbf;
    __syncthreads();

#define P0KT(KT)                                                                \
    do {                                                                        \
        a0 = MFMA_FP8(wreg8[KT], hf[KT], (KT) ? a0 : Z, 0, 0, 0);               \
        a1 = MFMA_FP8(wreg8[9 + (KT)], hf[KT], (KT) ? a1 : Z, 0, 0, 0);         \
        a2 = MFMA_FP8(*(const fp8frag*)&wlds8[w][KT][l * 8], hf[KT], (KT) ? a2 : Z, 0, 0, 0);       \
        a3 = MFMA_FP8(*(const fp8frag*)&wlds8[w][9 + (KT)][l * 8], hf[KT], (KT) ? a3 : Z, 0, 0, 0); \
    } while (0)

#define P1KT(KT, NXT, USE, PF)                                                  \
    do {                                                                        \
        PF = *(const fp8frag*)(pc7 + ((NXT) - 4) * 512);                        \
        a4 = MFMA_FP8(wreg8[18 + (KT)], hf[KT], (KT) ? a4 : Z, 0, 0, 0);        \
        a5 = MFMA_FP8(wreg8[27 + (KT)], hf[KT], (KT) ? a5 : Z, 0, 0, 0);        \
        a6 = MFMA_FP8(wreg8[36 + (KT)], hf[KT], (KT) ? a6 : Z, 0, 0, 0);        \
        a7 = MFMA_FP8(USE, hf[KT], (KT) ? a7 : Z, 0, 0, 0);                     \
    } while (0)

// group-A cell (this step's gates a0-a3)
#define EWAC(J)                                                                 \
    do {                                                                        \
        float gi_ = a0[J] * DS1c, gf_ = a1[J] * DS1c;                           \
        float gg_ = a2[J] * DS2c, go_ = a3[J] * DS1c;                           \
        float cn_ = fmaf(SGg(gf_), c[J], SGg(gi_) * THg(gg_));                  \
        c[J] = cn_;                                                             \
        hA[J] = SGg(go_) * THg(cn_ * TL2E);                                     \
    } while (0)

// deferred group-B cell (PREVIOUS step's gates sa4-sa7)
#define EWBC(J)                                                                 \
    do {                                                                        \
        float gi_ = sa4[J] * DS1c, gf_ = sa5[J] * DS1c;                         \
        float gg_ = sa6[J] * DS2c, go_ = sa7[J] * DS1c;                         \
        float cn_ = fmaf(SGg(gf_), c[4 + (J)], SGg(gi_) * THg(gg_));            \
        c[4 + (J)] = cn_;                                                       \
        hB[J] = SGg(go_) * THg(cn_ * TL2E);                                     \
    } while (0)

#define WRH(PB, HV, U)                                                          \
    do {                                                                        \
        bf16x4 hb_ = {(__bf16)HV[0], (__bf16)HV[1], (__bf16)HV[2], (__bf16)HV[3]};\
        *(bf16x4*)&hbuf[PB][arow][U] = hb_;                                     \
        int pk_ = __builtin_amdgcn_cvt_pk_fp8_f32(HV[0] * 16.f, HV[1] * 16.f, 0, false);\
        pk_ = __builtin_amdgcn_cvt_pk_fp8_f32(HV[2] * 16.f, HV[3] * 16.f, pk_, true);  \
        *(int*)&hbuf8[PB][arow][U] = pk_;                                       \
    } while (0)

// heads split: HP1 = kt{0,1,2,3,8} (cols 0-127 + bias col, valid in phase1),
// HP2 = kt{4,5,6,7} (cols 128-255, valid after mid-barrier) + store.
#define HP1(RB)                                                                 \
    do {                                                                        \
        bf16x8 hb_ = *(const bf16x8*)&hbuf[RB][arow][0 * 32 + ako];             \
        ahh = MFMA_BF16(*(const bf16x8*)&headw[0][l * 8], hb_, Z, 0, 0, 0);     \
        hb_ = *(const bf16x8*)&hbuf[RB][arow][1 * 32 + ako];                    \
        ahh = MFMA_BF16(*(const bf16x8*)&headw[1][l * 8], hb_, ahh, 0, 0, 0);   \
        hb_ = *(const bf16x8*)&hbuf[RB][arow][2 * 32 + ako];                    \
        ahh = MFMA_BF16(*(const bf16x8*)&headw[2][l * 8], hb_, ahh, 0, 0, 0);   \
        hb_ = *(const bf16x8*)&hbuf[RB][arow][3 * 32 + ako];                    \
        ahh = MFMA_BF16(*(const bf16x8*)&headw[3][l * 8], hb_, ahh, 0, 0, 0);   \
        hb_ = *(const bf16x8*)&hbuf[RB][arow][8 * 32 + ako];                    \
        ahh = MFMA_BF16(*(const bf16x8*)&headw[8][l * 8], hb_, ahh, 0, 0, 0);   \
    } while (0)

#define HP2(RB, SLOT)                                                           \
    do {                                                                        \
        bf16x8 hb_ = *(const bf16x8*)&hbuf[RB][arow][4 * 32 + ako];             \
        ahh = MFMA_BF16(*(const bf16x8*)&headw[4][l * 8], hb_, ahh, 0, 0, 0);   \
        hb_ = *(const bf16x8*)&hbuf[RB][arow][5 * 32 + ako];                    \
        ahh = MFMA_BF16(*(const bf16x8*)&headw[5][l * 8], hb_, ahh, 0, 0, 0);   \
        hb_ = *(const bf16x8*)&hbuf[RB][arow][6 * 32 + ako];                    \
        ahh = MFMA_BF16(*(const bf16x8*)&headw[6][l * 8], hb_, ahh, 0, 0, 0);   \
        hb_ = *(const bf16x8*)&hbuf[RB][arow][7 * 32 + ako];                    \
        ahh = MFMA_BF16(*(const bf16x8*)&headw[7][l * 8], hb_, ahh, 0, 0, 0);   \
        if (l < 16) {                                                           \
            obuf[0][l][SLOT] = ahh[0];                                          \
            obuf[1][l][SLOT] = fminf(fmaxf(ahh[1], -10.f), 2.f);                \
        }                                                                       \
    } while (0)

#define FLUSH(T0)                                                               \
    do {                                                                        \
        if (tid < 192) {                                                        \
            const int o_ = tid >> 6, rr_ = (tid >> 2) & 15, q_ = tid & 3;       \
            f32x4 mv_ = *(const f32x4*)&obuf[0][rr_][q_ * 4];                   \
            f32x4 lv_ = *(const f32x4*)&obuf[1][rr_][q_ * 4];                   \
            const size_t base_ = (size_t)(m0 + rr_) * TT + (T0) + q_ * 4;       \
            if (o_ == 0) {                                                      \
                f32x4 e_ = *(const f32x4*)&eps[base_];                          \
                f32x4 s_;                                                       \
                _Pragma("unroll")                                               \
                for (int k_ = 0; k_ < 4; ++k_)                                  \
                    s_[k_] = fmaf(EXP2F(lv_[k_] * HL2E), e_[k_], mv_[k_]);      \
                *(f32x4*)&out[base_] = s_;                                      \
            } else if (o_ == 1) {                                               \
                *(f32x4*)&out[(size_t)BB * TT + base_] = mv_;                   \
            } else {                                                            \
                *(f32x4*)&out[2 * (size_t)BB * TT + base_] = lv_;               \
            }                                                                   \
        }                                                                       \
    } while (0)

#define STEP(PB, RB, BA, BX)                                                    \
    do {                                                                        \
        const int tt = t0 + (PB);                                               \
        float xn = 0.f;                                                         \
        if (tid < 16 && tt + 1 < TT) xn = x[(size_t)(m0 + tid) * TT + (tt + 1)];\
        fp8frag hf[9];                                                          \
        hf[0] = *(const fp8frag*)&hbuf8[RB][arow][0 * 32 + ako];                \
        hf[1] = *(const fp8frag*)&hbuf8[RB][arow][1 * 32 + ako];                \
        hf[2] = *(const fp8frag*)&hbuf8[RB][arow][2 * 32 + ako];                \
        hf[3] = *(const fp8frag*)&hbuf8[RB][arow][3 * 32 + ako];                \
        hf[8] = *(const fp8frag*)&hbuf8[RB][arow][8 * 32 + ako];                \
        f32x4 a0, a1, a2, a3, a4, a5, a6, a7, ahh;                              \
        float hA[4], hB[4];                                                     \
        /* ---- phase 1: kt {0,1,2,3,8}; deferred EWB(t-1) hidden under ---- */ \
        P0KT(0); P1KT(0, 1, BA, BX);                                            \
        if (tt > 0) EWBC(0);                                                    \
        P0KT(1); P1KT(1, 2, BX, BA);                                            \
        if (tt > 0) EWBC(1);                                                    \
        P0KT(2); P1KT(2, 3, BA, BX);                                            \
        if (tt > 0) EWBC(2);                                                    \
        P0KT(3); P1KT(3, 8, BX, BA);                                            \
        if (tt > 0) EWBC(3);                                                    \
        P0KT(8); P1KT(8, 4, BA, BX);                                            \
        if (w == 7 && tt >= 1) HP1(RB);                                         \
        if (tt > 0) WRH(RB, hB, u1);                                            \
        __syncthreads();                                                        \
        /* ---- phase 2: kt {4,5,6,7}; EWA interleaved into a4-a7 chains --- */ \
        hf[4] = *(const fp8frag*)&hbuf8[RB][arow][4 * 32 + ako];                \
        hf[5] = *(const fp8frag*)&hbuf8[RB][arow][5 * 32 + ako];                \
        hf[6] = *(const fp8frag*)&hbuf8[RB][arow][6 * 32 + ako];                \
        hf[7] = *(const fp8frag*)&hbuf8[RB][arow][7 * 32 + ako];                \
        P0KT(4); P0KT(5); P0KT(6); P0KT(7);                                     \
        if (w == 7 && tt >= 1) HP2(RB, (tt - 1) & 15);                          \
        P1KT(4, 5, BX, BA); EWAC(0);                                            \
        P1KT(5, 6, BA, BX); EWAC(1);                                            \
        P1KT(6, 7, BX, BA); EWAC(2);                                            \
        P1KT(7, 0, BA, BX); EWAC(3);                                            \
        sa4 = a4; sa5 = a5; sa6 = a6; sa7 = a7;                                 \
        WRH(PB, hA, u0);                                                        \
        if (tid < 16 && tt + 1 < TT) {                                          \
            hbuf[PB][tid][256] = (__bf16)xn;                                    \
            hbuf8[PB][tid][256] =                                               \
                (char)__builtin_amdgcn_cvt_pk_fp8_f32(xn * 16.f, 0.f, 0, false);\
        }                                                                       \
        if ((PB) == 0 && tt > 0 && (tt & 15) == 0) {                            \
            __syncthreads();                                                    \
            FLUSH(tt - 16);                                                     \
        }                                                                       \
        __syncthreads();                                                        \
    } while (0)

    for (int t0 = 0; t0 < TT; t0 += 2) {
        STEP(0, 1, sbf, tbf);
        STEP(1, 0, tbf, sbf);
    }

    // ---- tail: finish deferred h_B(TT-1), then heads + final flush ----
    {
        float hB[4];
        EWBC(0); EWBC(1); EWBC(2); EWBC(3);
        WRH(1, hB, u1);
        __syncthreads();
        if (w == 7) {
            f32x4 ahh;
            HP1(1);
            HP2(1, 15);
        }
        __syncthreads();
        FLUSH(TT - 16);
    }

#undef P0KT
#undef P1KT
#undef EWAC
#undef EWBC
#undef WRH
#undef HP1
#undef HP2
#undef FLUSH
#undef STEP
}

extern "C" void kernel_launch(void* const* d_in, const int* in_sizes, int n_in,
                              void* d_out, int out_size, void* d_ws, size_t ws_size,
                              hipStream_t stream) {
    const float* x = (const float*)d_in[0];
    const float* eps = (const float*)d_in[1];
    const float* w_ih = (const float*)d_in[2];
    const float* w_hh = (const float*)d_in[3];
    const float* b_ih = (const float*)d_in[4];
    const float* b_hh = (const float*)d_in[5];
    const float* w_mean = (const float*)d_in[6];
    const float* b_mean = (const float*)d_in[7];
    const float* w_logvar = (const float*)d_in[8];
    const float* b_logvar = (const float*)d_in[9];

    char* wB8 = (char*)d_ws;  // 288 KB fp8 A-frag weights (x64, K=288 fold)

    prep_weights8<<<144, 256, 0, stream>>>(w_hh, w_ih, b_ih, b_hh, wB8);
    lstm_fused<<<256, 512, 0, stream>>>(x, eps, w_mean, b_mean, w_logvar, b_logvar,
                                        wB8, (float*)d_out);
}

// Round 15
// 880.795 us; speedup vs baseline: 1.2226x; 1.2214x over previous
//
#include <hip/hip_runtime.h>
#include <hip/hip_bf16.h>

#define BB 4096
#define TT 512
#define HH 256

typedef __bf16 bf16x8 __attribute__((ext_vector_type(8)));
typedef __bf16 bf16x4 __attribute__((ext_vector_type(4)));
typedef float f32x4 __attribute__((ext_vector_type(4)));
typedef int i32x8 __attribute__((ext_vector_type(8)));
typedef long fp8frag;  // 8 x e4m3 in 2 VGPRs

#define MFMA_BF16 __builtin_amdgcn_mfma_f32_16x16x32_bf16
#define MFMA_FP8  __builtin_amdgcn_mfma_f32_16x16x32_fp8_fp8
// K=128 block-scaled fp8 MFMA, scales = 1.0 (e8m0 0x7F), fmt A/B = fp8 e4m3.
// 2x the FLOP rate of the K=32 form -> halves the per-step MFMA pipe time.
#define MFMA_SC(A, B, C) \
    __builtin_amdgcn_mfma_scale_f32_16x16x128_f8f6f4( \
        A, B, C, 0, 0, 0, 0x7F7F7F7F, 0, 0x7F7F7F7F)

#if defined(__has_builtin)
#if __has_builtin(__builtin_amdgcn_exp2f)
#define EXP2F(x) __builtin_amdgcn_exp2f(x)
#endif
#endif
#ifndef EXP2F
#define EXP2F(x) __expf((x) * 0.6931471805599453f)
#endif
#define RCPF(x) __builtin_amdgcn_rcpf(x)

#define L2E  1.4426950408889634f
#define TL2E 2.8853900817779268f   // 2*log2e
#define HL2E 0.7213475204444817f   // 0.5*log2e

// Weight prep (r15): two fragment families, both A-operand (operand-swap).
// BIG (K=128 scaled): lane l, byte e -> 64*W[ctg*16+(l&15)][kb*128+(l>>4)*32+e]
//   at wB8[((ctg*2+kb)*64+l)*32+e], 262144 B.
// SMALL (K=32, kt8 = x/bias fold): lane l, e -> k=256+8*(l>>4)+e:
//   k=256 -> 64*w_ih, k=257 -> 64*(b_ih+b_hh), else 0;
//   at wB8[262144 + (ctg*64+l)*8 + e], 32768 B.
__global__ void prep_weights8(const float* __restrict__ w_hh, const float* __restrict__ w_ih,
                              const float* __restrict__ b_ih, const float* __restrict__ b_hh,
                              char* __restrict__ wB8) {
    int idx = blockIdx.x * blockDim.x + threadIdx.x;
    if (idx < 64 * 2 * 64) {
        int l = idx & 63;
        int kb = (idx >> 6) & 1;
        int ctg = idx >> 7;
        int n = ctg * 16 + (l & 15);
        int k0 = kb * 128 + (l >> 4) * 32;
        const float* src = w_hh + n * HH + k0;
        i32x8 v;
#pragma unroll
        for (int d = 0; d < 8; ++d) {
            int pk = __builtin_amdgcn_cvt_pk_fp8_f32(src[4 * d] * 64.f,
                                                     src[4 * d + 1] * 64.f, 0, false);
            pk = __builtin_amdgcn_cvt_pk_fp8_f32(src[4 * d + 2] * 64.f,
                                                 src[4 * d + 3] * 64.f, pk, true);
            v[d] = pk;
        }
        *(i32x8*)(wB8 + (size_t)idx * 32) = v;
    } else if (idx < 64 * 2 * 64 + 64 * 64) {
        int j = idx - 64 * 2 * 64;
        int l = j & 63;
        int ctg = j >> 6;
        int n = ctg * 16 + (l & 15);
        int k0 = 256 + 8 * (l >> 4);
        float f[8];
#pragma unroll
        for (int e = 0; e < 8; ++e) {
            int k = k0 + e;
            float v = 0.f;
            if (k == 256) v = w_ih[n];
            else if (k == 257) v = b_ih[n] + b_hh[n];
            f[e] = v * 64.f;
        }
        int lo = __builtin_amdgcn_cvt_pk_fp8_f32(f[0], f[1], 0, false);
        lo = __builtin_amdgcn_cvt_pk_fp8_f32(f[2], f[3], lo, true);
        int hi = __builtin_amdgcn_cvt_pk_fp8_f32(f[4], f[5], 0, false);
        hi = __builtin_amdgcn_cvt_pk_fp8_f32(f[6], f[7], hi, true);
        int2 v2; v2.x = lo; v2.y = hi;
        *(int2*)(wB8 + 262144 + (size_t)j * 8) = v2;
    }
}

// exp2-domain activations (v_exp_f32 IS 2^x); inputs pre-scaled by log2e.
#define SGg(v) RCPF(1.f + EXP2F(-(v)))
#define THg(v) (1.f - 2.f * RCPF(EXP2F(v) + 1.f))

// r15: all weights VGPR-resident (wbig 16 frags = 128 regs, wsm 8 = 16 regs);
// no wlds, no L2 stream. MFMA/wave: 16 scaled K=128 + 8 plain K=32 = 24
// (was 72). hbuf8 stride 304 (16-B aligned rows for the 32-B/lane reads).
__global__ __launch_bounds__(512, 1) void lstm_fused(
    const float* __restrict__ x, const float* __restrict__ eps,
    const float* __restrict__ w_mean, const float* __restrict__ b_mean,
    const float* __restrict__ w_logvar, const float* __restrict__ b_logvar,
    const char* __restrict__ wB8, float* __restrict__ out)
{
    __shared__ __align__(16) __bf16 hbuf[2][16][296];   // 18944 B: bf16 h|x|1 (heads)
    __shared__ __align__(16) char hbuf8[2][16][304];    // 9728 B: fp8 (h|x)*16, 1*16
    __shared__ __align__(16) __bf16 headw[9][512];      // 9216 B
    __shared__ float obuf[2][16][16];                   // 2048 B: mean, logvar(clipped)
    // total 39936 B

    const int tid = threadIdx.x;
    const int w = tid >> 6;          // wave 0..7
    const int l = tid & 63;
    const int m0 = blockIdx.x * 16;

    for (int i = tid; i < 2 * 16 * 296; i += 512) (&hbuf[0][0][0])[i] = (__bf16)0.f;
    for (int i = tid; i < 2 * 16 * 304; i += 512) (&hbuf8[0][0][0])[i] = 0;
    // headw A-frags: row 0 = w_mean, row 1 = w_logvar (k=257 -> biases), bf16
    for (int i = tid; i < 9 * 64; i += 512) {
        int kt = i >> 6, hl = i & 63;
        int col = hl & 15;
        int k0 = kt * 32 + 8 * (hl >> 4);
        bf16x8 hw;
#pragma unroll
        for (int e = 0; e < 8; ++e) {
            int k = k0 + e;
            float v = 0.f;
            if (k < 256) {
                if (col == 0) v = w_mean[k];
                else if (col == 1) v = w_logvar[k];
            } else if (k == 257) {
                if (col == 0) v = b_mean[0];
                else if (col == 1) v = b_logvar[0];
            }
            hw[e] = (__bf16)v;
        }
        *(bf16x8*)&headw[kt][hl * 8] = hw;
    }

    // wave w owns ctg = w + 8p + 16g for cc = p*4+g; ALL weights in registers.
    i32x8 wbig[16];
    fp8frag wsm[8];
#pragma unroll
    for (int cc = 0; cc < 8; ++cc) {
        const int ctg = w + 8 * (cc >> 2) + 16 * (cc & 3);
        wbig[2 * cc]     = *(const i32x8*)(wB8 + ((size_t)(ctg * 2 + 0) * 64 + l) * 32);
        wbig[2 * cc + 1] = *(const i32x8*)(wB8 + ((size_t)(ctg * 2 + 1) * 64 + l) * 32);
        wsm[cc] = *(const fp8frag*)(wB8 + 262144 + ((size_t)ctg * 64 + l) * 8);
    }

    const int arow = l & 15;
    const int a32 = 32 * (l >> 4);   // K=128 chunk offset (32 B/lane)
    const int ak8 = 8 * (l >> 4);    // K=32 kt8 offset
    const int ako = 16 * (l >> 4);   // bf16 head frag elem offset (8 elems)
    const int u0 = 16 * w + ((l >> 4) << 2);   // 4 consecutive units
    const int u1 = u0 + 128;

    const float DS1c = L2E / 1024.f;   // acc descale * log2e
    const float DS2c = TL2E / 1024.f;  // acc descale * 2*log2e (g-gate)

    float c[8];
#pragma unroll
    for (int i = 0; i < 8; ++i) c[i] = 0.f;
    const f32x4 Z = {0.f, 0.f, 0.f, 0.f};

    __syncthreads();
    if (tid < 16) {
        hbuf[0][tid][257] = (__bf16)1.0f;
        hbuf[1][tid][257] = (__bf16)1.0f;
        hbuf8[0][tid][257] = (char)__builtin_amdgcn_cvt_pk_fp8_f32(16.f, 0.f, 0, false);
        hbuf8[1][tid][257] = (char)__builtin_amdgcn_cvt_pk_fp8_f32(16.f, 0.f, 0, false);
        float x0 = x[(size_t)(m0 + tid) * TT];
        hbuf[1][tid][256] = (__bf16)x0;                 // rb of t=0 is buf 1
        hbuf8[1][tid][256] = (char)__builtin_amdgcn_cvt_pk_fp8_f32(x0 * 16.f, 0.f, 0, false);
    }
    __syncthreads();

// group-A cell (gates a0-a3)
#define EWAC(J)                                                                 \
    do {                                                                        \
        float gi_ = a0[J] * DS1c, gf_ = a1[J] * DS1c;                           \
        float gg_ = a2[J] * DS2c, go_ = a3[J] * DS1c;                           \
        float cn_ = fmaf(SGg(gf_), c[J], SGg(gi_) * THg(gg_));                  \
        c[J] = cn_;                                                             \
        hA[J] = SGg(go_) * THg(cn_ * TL2E);                                     \
    } while (0)

// group-B cell (gates a4-a7)
#define EWBC(J)                                                                 \
    do {                                                                        \
        float gi_ = a4[J] * DS1c, gf_ = a5[J] * DS1c;                           \
        float gg_ = a6[J] * DS2c, go_ = a7[J] * DS1c;                           \
        float cn_ = fmaf(SGg(gf_), c[4 + (J)], SGg(gi_) * THg(gg_));            \
        c[4 + (J)] = cn_;                                                       \
        hB[J] = SGg(go_) * THg(cn_ * TL2E);                                     \
    } while (0)

#define WRH(PB, HV, U)                                                          \
    do {                                                                        \
        bf16x4 hb_ = {(__bf16)HV[0], (__bf16)HV[1], (__bf16)HV[2], (__bf16)HV[3]};\
        *(bf16x4*)&hbuf[PB][arow][U] = hb_;                                     \
        int pk_ = __builtin_amdgcn_cvt_pk_fp8_f32(HV[0] * 16.f, HV[1] * 16.f, 0, false);\
        pk_ = __builtin_amdgcn_cvt_pk_fp8_f32(HV[2] * 16.f, HV[3] * 16.f, pk_, true);  \
        *(int*)&hbuf8[PB][arow][U] = pk_;                                       \
    } while (0)

#define HEADS(RB, SLOT)                                                         \
    do {                                                                        \
        f32x4 ah_;                                                              \
        {                                                                       \
            bf16x8 hb_ = *(const bf16x8*)&hbuf[RB][arow][0 * 32 + ako / 2];     \
            ah_ = MFMA_BF16(*(const bf16x8*)&headw[0][l * 8], hb_, Z, 0, 0, 0); \
        }                                                                       \
        _Pragma("unroll")                                                       \
        for (int kt_ = 1; kt_ < 9; ++kt_) {                                     \
            bf16x8 hb_ = *(const bf16x8*)&hbuf[RB][arow][kt_ * 32 + ako / 2];   \
            ah_ = MFMA_BF16(*(const bf16x8*)&headw[kt_][l * 8], hb_, ah_, 0, 0, 0);\
        }                                                                       \
        if (l < 16) {                                                           \
            obuf[0][l][SLOT] = ah_[0];                                          \
            obuf[1][l][SLOT] = fminf(fmaxf(ah_[1], -10.f), 2.f);                \
        }                                                                       \
    } while (0)

#define FLUSH(T0)                                                               \
    do {                                                                        \
        if (tid < 192) {                                                        \
            const int o_ = tid >> 6, rr_ = (tid >> 2) & 15, q_ = tid & 3;       \
            f32x4 mv_ = *(const f32x4*)&obuf[0][rr_][q_ * 4];                   \
            f32x4 lv_ = *(const f32x4*)&obuf[1][rr_][q_ * 4];                   \
            const size_t base_ = (size_t)(m0 + rr_) * TT + (T0) + q_ * 4;       \
            if (o_ == 0) {                                                      \
                f32x4 e_ = *(const f32x4*)&eps[base_];                          \
                f32x4 s_;                                                       \
                _Pragma("unroll")                                               \
                for (int k_ = 0; k_ < 4; ++k_)                                  \
                    s_[k_] = fmaf(EXP2F(lv_[k_] * HL2E), e_[k_], mv_[k_]);      \
                *(f32x4*)&out[base_] = s_;                                      \
            } else if (o_ == 1) {                                               \
                *(f32x4*)&out[(size_t)BB * TT + base_] = mv_;                   \
            } else {                                                            \
                *(f32x4*)&out[2 * (size_t)BB * TT + base_] = lv_;               \
            }                                                                   \
        }                                                                       \
    } while (0)

#define STEP(PB, RB)                                                            \
    do {                                                                        \
        const int tt = t0 + (PB);                                               \
        float xn = 0.f;                                                         \
        if (tid < 16 && tt + 1 < TT) xn = x[(size_t)(m0 + tid) * TT + (tt + 1)];\
        i32x8 hf0 = *(const i32x8*)&hbuf8[RB][arow][a32];                       \
        i32x8 hf1 = *(const i32x8*)&hbuf8[RB][arow][128 + a32];                 \
        fp8frag hf8 = *(const fp8frag*)&hbuf8[RB][arow][256 + ak8];             \
        f32x4 a0, a1, a2, a3, a4, a5, a6, a7;                                   \
        float hA[4], hB[4];                                                     \
        /* P0: group-A gate chains (cc0-3), 3 MFMAs each, 4-way ILP */          \
        a0 = MFMA_SC(wbig[0], hf0, Z);  a1 = MFMA_SC(wbig[2], hf0, Z);          \
        a2 = MFMA_SC(wbig[4], hf0, Z);  a3 = MFMA_SC(wbig[6], hf0, Z);          \
        a0 = MFMA_SC(wbig[1], hf1, a0); a1 = MFMA_SC(wbig[3], hf1, a1);         \
        a2 = MFMA_SC(wbig[5], hf1, a2); a3 = MFMA_SC(wbig[7], hf1, a3);         \
        a0 = MFMA_FP8(wsm[0], hf8, a0, 0, 0, 0);                                \
        a1 = MFMA_FP8(wsm[1], hf8, a1, 0, 0, 0);                                \
        a2 = MFMA_FP8(wsm[2], hf8, a2, 0, 0, 0);                                \
        a3 = MFMA_FP8(wsm[3], hf8, a3, 0, 0, 0);                                \
        /* P1: group-B chains (cc4-7) with EW(A) interleaved */                 \
        a4 = MFMA_SC(wbig[8], hf0, Z);  a5 = MFMA_SC(wbig[10], hf0, Z);         \
        a6 = MFMA_SC(wbig[12], hf0, Z); a7 = MFMA_SC(wbig[14], hf0, Z);         \
        EWAC(0);                                                                \
        a4 = MFMA_SC(wbig[9], hf1, a4); a5 = MFMA_SC(wbig[11], hf1, a5);        \
        EWAC(1);                                                                \
        a6 = MFMA_SC(wbig[13], hf1, a6); a7 = MFMA_SC(wbig[15], hf1, a7);       \
        EWAC(2);                                                                \
        a4 = MFMA_FP8(wsm[4], hf8, a4, 0, 0, 0);                                \
        a5 = MFMA_FP8(wsm[5], hf8, a5, 0, 0, 0);                                \
        a6 = MFMA_FP8(wsm[6], hf8, a6, 0, 0, 0);                                \
        a7 = MFMA_FP8(wsm[7], hf8, a7, 0, 0, 0);                                \
        EWAC(3);                                                                \
        WRH(PB, hA, u0);                                                        \
        if (w == 7 && tt >= 1) { HEADS(RB, (tt - 1) & 15); }                    \
        EWBC(0); EWBC(1); EWBC(2); EWBC(3);                                     \
        WRH(PB, hB, u1);                                                        \
        if (tid < 16 && tt + 1 < TT) {                                          \
            hbuf[PB][tid][256] = (__bf16)xn;                                    \
            hbuf8[PB][tid][256] =                                               \
                (char)__builtin_amdgcn_cvt_pk_fp8_f32(xn * 16.f, 0.f, 0, false);\
        }                                                                       \
        if ((PB) == 0 && tt > 0 && (tt & 15) == 0) {                            \
            __syncthreads();                                                    \
            FLUSH(tt - 16);                                                     \
        }                                                                       \
        __syncthreads();                                                        \
    } while (0)

    for (int t0 = 0; t0 < TT; t0 += 2) {
        STEP(0, 1);
        STEP(1, 0);
    }

    // ---- tail: head for h_{TT-1} (in hbuf[1]) + final flush ----
    if (w == 7) { HEADS(1, 15); }
    __syncthreads();
    FLUSH(TT - 16);

#undef EWAC
#undef EWBC
#undef WRH
#undef HEADS
#undef FLUSH
#undef STEP
}

extern "C" void kernel_launch(void* const* d_in, const int* in_sizes, int n_in,
                              void* d_out, int out_size, void* d_ws, size_t ws_size,
                              hipStream_t stream) {
    const float* x = (const float*)d_in[0];
    const float* eps = (const float*)d_in[1];
    const float* w_ih = (const float*)d_in[2];
    const float* w_hh = (const float*)d_in[3];
    const float* b_ih = (const float*)d_in[4];
    const float* b_hh = (const float*)d_in[5];
    const float* w_mean = (const float*)d_in[6];
    const float* b_mean = (const float*)d_in[7];
    const float* w_logvar = (const float*)d_in[8];
    const float* b_logvar = (const float*)d_in[9];

    char* wB8 = (char*)d_ws;  // 288 KB fp8 weights: K=128 scaled frags + kt8 frags

    prep_weights8<<<48, 256, 0, stream>>>(w_hh, w_ih, b_ih, b_hh, wB8);
    lstm_fused<<<256, 512, 0, stream>>>(x, eps, w_mean, b_mean, w_logvar, b_logvar,
                                        wB8, (float*)d_out);
}